// Round 2
// baseline (80.255 us; speedup 1.0000x reference)
//
#include <hip/hip_runtime.h>

#define BLOCK 256
#define PTS_PER_BLOCK 512          // 2 points per thread
#define NPTS (8 * 65536)

// One thread owns 2 consecutive points end-to-end. NO LDS anywhere:
// the MLP weights are read with uniform index h from const-restrict memory,
// so the compiler emits s_load through the scalar/constant cache (separate
// pipe from LDS). With unroll 8, consecutive W1 rows (128B) merge into
// s_load_dwordx16; W2/b1 into dwordx8 — ~5 scalar loads per 8 iterations.
// Weights (3.5 KB) are scalar-cache resident across all blocks.
// Global IO is vectorized: input 3x dwordx2, eval dwordx2, con 2x dwordx4,
// probs dwordx4.

__global__ __launch_bounds__(BLOCK, 4) void cubeflow_fused(
    const float* __restrict__ input,
    const float* __restrict__ latent,
    const float* __restrict__ W1,
    const float* __restrict__ b1,
    const float* __restrict__ W2,
    const float* __restrict__ b2,
    float* __restrict__ out)
{
    const int t     = threadIdx.x;
    const int base  = blockIdx.x * PTS_PER_BLOCK;
    const int batch = base >> 16;                 // 128 blocks per batch
    const float theta = latent[batch] * 10.0f;    // uniform per block

    // ---- load this thread's 2 points: 3x float2 (8B aligned) ----
    const int p0 = base + 2 * t;
    const float2* ip = reinterpret_cast<const float2*>(input + 3 * p0);
    const float2 f0 = ip[0];
    const float2 f1 = ip[1];
    const float2 f2 = ip[2];
    const float x0a = f0.x, x1a = f0.y, x2a = f1.x;
    const float x0b = f1.y, x1b = f2.x, x2b = f2.y;

    float* __restrict__ out_eval  = out;             // NPTS
    float* __restrict__ out_con   = out + NPTS;      // NPTS*4
    float* __restrict__ out_probs = out + 5 * NPTS;  // NPTS*2

    // ---- eval + con (fp32, exact) ----
    {
        const float cth = cosf(theta);
        const float sth = sinf(theta);

        const float d0a = x0a - theta, d1a = x1a, d2a = x2a;
        const float d0b = x0b - theta, d1b = x1b, d2b = x2b;

        const float f1a = fmaf(1.4f * d0a, d0a, fmaf(1.4f * d1a, d1a, 0.2f * d2a * d2a)) - 0.5f;
        const float f1b = fmaf(1.4f * d0b, d0b, fmaf(1.4f * d1b, d1b, 0.2f * d2b * d2b)) - 0.5f;

        const float c2xa = fmaf(cth, d0a,  sth * d1a);
        const float c2ya = fmaf(cth, d1a, -sth * d0a);
        const float c2za = d2a + 0.4f;
        const float f2a = fmaf(3.8f * c2xa, c2xa, fmaf(0.6f * c2ya, c2ya, 3.8f * c2za * c2za)) - 0.5f;
        const float c2xb = fmaf(cth, d0b,  sth * d1b);
        const float c2yb = fmaf(cth, d1b, -sth * d0b);
        const float c2zb = d2b + 0.4f;
        const float f2b = fmaf(3.8f * c2xb, c2xb, fmaf(0.6f * c2yb, c2yb, 3.8f * c2zb * c2zb)) - 0.5f;

        const float c3xa = fmaf(cth, d0a, -sth * d1a);
        const float c3ya = fmaf(sth, d0a,  cth * d1a);
        const float c3za = d2a - 0.6f;
        const float f3a = fmaf(0.35f * c3xa, c3xa, fmaf(2.8f * c3ya, c3ya, 2.8f * c3za * c3za)) - 0.5f;
        const float c3xb = fmaf(cth, d0b, -sth * d1b);
        const float c3yb = fmaf(sth, d0b,  cth * d1b);
        const float c3zb = d2b - 0.6f;
        const float f3b = fmaf(0.35f * c3xb, c3xb, fmaf(2.8f * c3yb, c3yb, 2.8f * c3zb * c3zb)) - 0.5f;

        *reinterpret_cast<float2*>(out_eval + p0) =
            make_float2(fminf(f1a, fminf(f2a, f3a)), fminf(f1b, fminf(f2b, f3b)));

        float4* cp = reinterpret_cast<float4*>(out_con + 4 * p0);
        cp[0] = make_float4(x0a, x1a, x2a, theta);
        cp[1] = make_float4(x0b, x1b, x2b, theta);
    }

    // ---- MLP: 128 hidden units via scalar-uniform weight loads (no LDS) ----
    float a0a = 0.0f, a1a = 0.0f, a0b = 0.0f, a1b = 0.0f;
#pragma unroll 8
    for (int h = 0; h < 128; ++h) {
        const float w0 = W1[4 * h + 0];        // uniform -> s_load
        const float w1 = W1[4 * h + 1];
        const float w2 = W1[4 * h + 2];
        const float w3 = W1[4 * h + 3];
        const float bias = fmaf(theta, w3, b1[h]);   // fold per iteration (VALU)
        const float w20 = W2[h];
        const float w21 = W2[128 + h];

        float hva = fmaf(x0a, w0, fmaf(x1a, w1, fmaf(x2a, w2, bias)));
        float hvb = fmaf(x0b, w0, fmaf(x1b, w1, fmaf(x2b, w2, bias)));
        hva = fmaxf(hva, 0.0f);
        hvb = fmaxf(hvb, 0.0f);
        a0a = fmaf(hva, w20, a0a);
        a1a = fmaf(hva, w21, a1a);
        a0b = fmaf(hvb, w20, a0b);
        a1b = fmaf(hvb, w21, a1b);
    }

    const float B0 = b2[0];
    const float B1 = b2[1];
    *reinterpret_cast<float4*>(out_probs + 2 * p0) =
        make_float4(a0a + B0, a1a + B1, a0b + B0, a1b + B1);
}

extern "C" void kernel_launch(void* const* d_in, const int* in_sizes, int n_in,
                              void* d_out, int out_size, void* d_ws, size_t ws_size,
                              hipStream_t stream) {
    const float* input  = (const float*)d_in[0];
    const float* latent = (const float*)d_in[1];
    const float* W1     = (const float*)d_in[2];
    const float* b1     = (const float*)d_in[3];
    const float* W2     = (const float*)d_in[4];
    const float* b2     = (const float*)d_in[5];
    float* out = (float*)d_out;

    const int nblocks = NPTS / PTS_PER_BLOCK;   // 1024
    hipLaunchKernelGGL(cubeflow_fused, dim3(nblocks), dim3(BLOCK), 0, stream,
                       input, latent, W1, b1, W2, b2, out);
}